// Round 1
// baseline (785.827 us; speedup 1.0000x reference)
//
#include <hip/hip_runtime.h>

typedef unsigned short ushort_t;
typedef short bf16x8 __attribute__((ext_vector_type(8)));
typedef float f32x4 __attribute__((ext_vector_type(4)));

__device__ __forceinline__ float bf2f(ushort_t u) {
    union { unsigned int i; float f; } v; v.i = ((unsigned int)u) << 16; return v.f;
}
__device__ __forceinline__ ushort_t f2bf(float f) {
    union { float f; unsigned int i; } v; v.f = f;
    unsigned int u = v.i;
    unsigned int r = (u + 0x7FFFu + ((u >> 16) & 1u)) >> 16;
    return (ushort_t)r;
}

// ---------------- fc_W -> bf16 ----------------
__global__ void k_convert(const float* __restrict__ w, ushort_t* __restrict__ o, int n) {
    int i = blockIdx.x * blockDim.x + threadIdx.x;
    if (i < n) o[i] = f2bf(w[i]);
}

// ---------------- encoder GRU: one block per sentence s ----------------
__global__ __launch_bounds__(384, 1) void k_encoder(
    const int* __restrict__ doc, const float* __restrict__ emb,
    const float* __restrict__ Wih, const float* __restrict__ Whh,
    const float* __restrict__ bih, const float* __restrict__ bhh,
    float* __restrict__ sent) {
    int s = blockIdx.x, j = threadIdx.x;
    __shared__ float x[64], h[128], gi[384], gh[384];
    float wih[64], whh[128];
#pragma unroll
    for (int k = 0; k < 64; k++) wih[k] = Wih[j * 64 + k];
#pragma unroll
    for (int k = 0; k < 128; k++) whh[k] = Whh[j * 128 + k];
    float bi = bih[j], bh = bhh[j];
    if (j < 128) h[j] = 0.f;
    __syncthreads();
    for (int t = 0; t < 48; t++) {
        if (j < 64) { int tok = doc[s * 48 + t]; x[j] = emb[tok * 64 + j]; }
        __syncthreads();
        float a = bi, b = bh;
#pragma unroll
        for (int k = 0; k < 64; k++) a += wih[k] * x[k];
#pragma unroll
        for (int k = 0; k < 128; k++) b += whh[k] * h[k];
        gi[j] = a; gh[j] = b;
        __syncthreads();
        if (j < 128) {
            float r = 1.f / (1.f + __expf(-(gi[j] + gh[j])));
            float z = 1.f / (1.f + __expf(-(gi[j + 128] + gh[j + 128])));
            float n = tanhf(gi[j + 256] + r * gh[j + 256]);
            h[j] = (1.f - z) * n + z * h[j];
        }
        __syncthreads();
    }
    if (j < 128) sent[s * 128 + j] = h[j];
}

// ---------------- doc-GRU input gates (parallel over steps) ----------------
__global__ void k_doc_gi(const float* __restrict__ sv, const float* __restrict__ Wih,
                         const float* __restrict__ bih, float* __restrict__ gidoc) {
    int i = blockIdx.x, j = threadIdx.x;
    __shared__ float v[128];
    if (j < 128) v[j] = sv[i * 128 + j];
    __syncthreads();
    float a = bih[j];
#pragma unroll 16
    for (int k = 0; k < 128; k++) a += Wih[j * 128 + k] * v[k];
    gidoc[i * 384 + j] = a;
}

// ---------------- doc GRU: single block, 128 sequential steps ----------------
__global__ __launch_bounds__(384, 1) void k_doc_seq(
    const float* __restrict__ gidoc, const float* __restrict__ Whh,
    const float* __restrict__ bhh, float* __restrict__ dvec) {
    int j = threadIdx.x;
    __shared__ float h[128], gi[384], gh[384];
    float whh[128];
#pragma unroll
    for (int k = 0; k < 128; k++) whh[k] = Whh[j * 128 + k];
    float bh = bhh[j];
    if (j < 128) h[j] = 0.f;
    __syncthreads();
    for (int i = 0; i < 128; i++) {
        float b = bh;
#pragma unroll
        for (int k = 0; k < 128; k++) b += whh[k] * h[k];
        gh[j] = b; gi[j] = gidoc[i * 384 + j];
        __syncthreads();
        if (j < 128) {
            float r = 1.f / (1.f + __expf(-(gi[j] + gh[j])));
            float z = 1.f / (1.f + __expf(-(gi[j + 128] + gh[j + 128])));
            float n = tanhf(gi[j + 256] + r * gh[j + 256]);
            h[j] = (1.f - z) * n + z * h[j];
        }
        __syncthreads();
    }
    if (j < 128) dvec[j] = h[j];
}

// ---------------- decoder context gate vector (same for every row) ----------------
__global__ void k_gctx(const float* __restrict__ Wih, const float* __restrict__ bih,
                       const float* __restrict__ dvec, float* __restrict__ gctx) {
    int j = threadIdx.x;
    __shared__ float v[128];
    if (j < 128) v[j] = dvec[j];
    __syncthreads();
    float a = bih[j];
#pragma unroll 16
    for (int k = 0; k < 128; k++) a += Wih[j * 192 + 64 + k] * v[k];
    gctx[j] = a;
}

// ---------------- decoder input gates (parallel over s,t) ----------------
__global__ __launch_bounds__(384, 1) void k_dec_gi(
    const int* __restrict__ doc, const float* __restrict__ emb,
    const float* __restrict__ Wih, const float* __restrict__ gctx,
    float* __restrict__ gidec) {
    int s = blockIdx.x, j = threadIdx.x;
    __shared__ float x[64];
    float wih[64];
#pragma unroll
    for (int k = 0; k < 64; k++) wih[k] = Wih[j * 192 + k];
    float g = gctx[j];
    for (int t = 0; t < 47; t++) {
        __syncthreads();
        if (j < 64) { int tok = doc[s * 48 + t]; x[j] = emb[tok * 64 + j]; }
        __syncthreads();
        float a = g;
#pragma unroll
        for (int k = 0; k < 64; k++) a += wih[k] * x[k];
        gidec[(t * 128 + s) * 384 + j] = a;
    }
}

// ---------------- decoder GRU: one block per sentence, stores h2 (bf16) ----------------
__global__ __launch_bounds__(384, 1) void k_dec_seq(
    const float* __restrict__ gidec, const float* __restrict__ Whh,
    const float* __restrict__ bhh, const float* __restrict__ sent,
    ushort_t* __restrict__ h2b) {
    int s = blockIdx.x, j = threadIdx.x;
    __shared__ float h[128], gi[384], gh[384];
    float whh[128];
#pragma unroll
    for (int k = 0; k < 128; k++) whh[k] = Whh[j * 128 + k];
    float bh = bhh[j];
    if (j < 128) h[j] = sent[s * 128 + j];
    __syncthreads();
    for (int t = 0; t < 47; t++) {
        float b = bh;
#pragma unroll
        for (int k = 0; k < 128; k++) b += whh[k] * h[k];
        gh[j] = b; gi[j] = gidec[(t * 128 + s) * 384 + j];
        __syncthreads();
        if (j < 128) {
            float r = 1.f / (1.f + __expf(-(gi[j] + gh[j])));
            float z = 1.f / (1.f + __expf(-(gi[j + 128] + gh[j + 128])));
            float n = tanhf(gi[j + 256] + r * gh[j + 256]);
            float hn = (1.f - z) * n + z * h[j];
            h[j] = hn;
            h2b[(t * 128 + s) * 128 + j] = f2bf(hn);
        }
        __syncthreads();
    }
}

// ---------------- target logits (one wave per row) ----------------
__global__ void k_tl(const int* __restrict__ doc, const ushort_t* __restrict__ h2b,
                     const ushort_t* __restrict__ wb, const float* __restrict__ fcb,
                     float* __restrict__ tl) {
    int r = blockIdx.x * 4 + (threadIdx.x >> 6);
    int lane = threadIdx.x & 63;
    int s = r & 127, t = r >> 7;
    int tok = doc[s * 48 + t + 1];
    const ushort_t* hp = h2b + r * 128;
    const ushort_t* wp = wb + tok * 128;
    float acc = bf2f(hp[lane]) * bf2f(wp[lane]) + bf2f(hp[lane + 64]) * bf2f(wp[lane + 64]);
#pragma unroll
    for (int m = 32; m >= 1; m >>= 1) acc += __shfl_xor(acc, m);
    if (lane == 0) tl[r] = acc + fcb[tok];
}

// ---------------- fused logits GEMM + sum(exp) over V-chunks ----------------
// grid: 47 rowblocks x 8 v-chunks; block 512 = 8 waves, wave owns 16 rows.
__global__ __launch_bounds__(512, 1) void k_lse(
    const ushort_t* __restrict__ h2b, const ushort_t* __restrict__ wb,
    const float* __restrict__ fcb, float* __restrict__ parts) {
    int rb = blockIdx.x >> 3;
    int vc = blockIdx.x & 7;
    int wave = threadIdx.x >> 6, lane = threadIdx.x & 63;
    int row0 = rb * 128 + wave * 16;

    bf16x8 a[4];
    const ushort_t* ap = h2b + (row0 + (lane & 15)) * 128 + (lane >> 4) * 8;
#pragma unroll
    for (int c = 0; c < 4; c++) a[c] = *(const bf16x8*)(ap + c * 32);

    float se0 = 0.f, se1 = 0.f, se2 = 0.f, se3 = 0.f;
    int colbase = vc * 4000;
    for (int tile = 0; tile < 250; tile += 2) {
        int cb0 = colbase + tile * 16;
        int cb1 = cb0 + 16;
        const ushort_t* bp0 = wb + (cb0 + (lane & 15)) * 128 + (lane >> 4) * 8;
        const ushort_t* bp1 = wb + (cb1 + (lane & 15)) * 128 + (lane >> 4) * 8;
        f32x4 acc0 = {0.f, 0.f, 0.f, 0.f}, acc1 = {0.f, 0.f, 0.f, 0.f};
#pragma unroll
        for (int c = 0; c < 4; c++) {
            bf16x8 b0 = *(const bf16x8*)(bp0 + c * 32);
            acc0 = __builtin_amdgcn_mfma_f32_16x16x32_bf16(a[c], b0, acc0, 0, 0, 0);
        }
#pragma unroll
        for (int c = 0; c < 4; c++) {
            bf16x8 b1 = *(const bf16x8*)(bp1 + c * 32);
            acc1 = __builtin_amdgcn_mfma_f32_16x16x32_bf16(a[c], b1, acc1, 0, 0, 0);
        }
        float bias0 = fcb[cb0 + (lane & 15)];
        float bias1 = fcb[cb1 + (lane & 15)];
        se0 += __expf(acc0[0] + bias0) + __expf(acc1[0] + bias1);
        se1 += __expf(acc0[1] + bias0) + __expf(acc1[1] + bias1);
        se2 += __expf(acc0[2] + bias0) + __expf(acc1[2] + bias1);
        se3 += __expf(acc0[3] + bias0) + __expf(acc1[3] + bias1);
    }
#pragma unroll
    for (int m = 1; m < 16; m <<= 1) {
        se0 += __shfl_xor(se0, m);
        se1 += __shfl_xor(se1, m);
        se2 += __shfl_xor(se2, m);
        se3 += __shfl_xor(se3, m);
    }
    if ((lane & 15) == 0) {
        int rbase = row0 + (lane >> 4) * 4;
        float* p = parts + vc * 6016;
        p[rbase + 0] = se0; p[rbase + 1] = se1; p[rbase + 2] = se2; p[rbase + 3] = se3;
    }
}

// ---------------- final reduction: loss = mean(log(sumexp) - target_logit) ----------------
__global__ void k_final(const float* __restrict__ parts, const float* __restrict__ tl,
                        float* __restrict__ out) {
    __shared__ float red[1024];
    int tid = threadIdx.x;
    float acc = 0.f;
    for (int r = tid; r < 6016; r += 1024) {
        float tot = 0.f;
#pragma unroll
        for (int vc = 0; vc < 8; vc++) tot += parts[vc * 6016 + r];
        acc += logf(tot) - tl[r];
    }
    red[tid] = acc;
    __syncthreads();
    for (int s = 512; s > 0; s >>= 1) {
        if (tid < s) red[tid] += red[tid + s];
        __syncthreads();
    }
    if (tid == 0) out[0] = red[0] / 6016.f;
}

extern "C" void kernel_launch(void* const* d_in, const int* in_sizes, int n_in,
                              void* d_out, int out_size, void* d_ws, size_t ws_size,
                              hipStream_t stream) {
    const int* doc = (const int*)d_in[0];
    const float* enc_emb = (const float*)d_in[1];
    const float* enc_Wih = (const float*)d_in[2];
    const float* enc_Whh = (const float*)d_in[3];
    const float* enc_bih = (const float*)d_in[4];
    const float* enc_bhh = (const float*)d_in[5];
    const float* doc_Wih = (const float*)d_in[6];
    const float* doc_Whh = (const float*)d_in[7];
    const float* doc_bih = (const float*)d_in[8];
    const float* doc_bhh = (const float*)d_in[9];
    const float* dec_emb = (const float*)d_in[10];
    const float* dec_Wih = (const float*)d_in[11];
    const float* dec_Whh = (const float*)d_in[12];
    const float* dec_bih = (const float*)d_in[13];
    const float* dec_bhh = (const float*)d_in[14];
    const float* fc_W = (const float*)d_in[15];
    const float* fc_b = (const float*)d_in[16];

    char* ws = (char*)d_ws;
    ushort_t* fcWb = (ushort_t*)(ws + 0);            // 8,192,000 B
    float* sent    = (float*)(ws + 8192000);         // 65,536 B
    float* dvec    = (float*)(ws + 8257536);         // 512 B
    float* gidoc   = (float*)(ws + 8258048);         // 196,608 B
    float* gctx    = (float*)(ws + 8454656);         // 1,536 B
    float* gidec   = (float*)(ws + 8456192);         // 9,240,576 B
    ushort_t* h2b  = (ushort_t*)(ws + 17696768);     // 1,540,096 B
    float* tl      = (float*)(ws + 19236864);        // 24,064 B
    float* parts   = (float*)(ws + 19260928);        // 192,512 B
    float* out = (float*)d_out;

    k_convert<<<16000, 256, 0, stream>>>(fc_W, fcWb, 4096000);
    k_encoder<<<128, 384, 0, stream>>>(doc, enc_emb, enc_Wih, enc_Whh, enc_bih, enc_bhh, sent);
    k_doc_gi<<<128, 384, 0, stream>>>(sent, doc_Wih, doc_bih, gidoc);
    k_doc_seq<<<1, 384, 0, stream>>>(gidoc, doc_Whh, doc_bhh, dvec);
    k_gctx<<<1, 384, 0, stream>>>(dec_Wih, dec_bih, dvec, gctx);
    k_dec_gi<<<128, 384, 0, stream>>>(doc, dec_emb, dec_Wih, gctx, gidec);
    k_dec_seq<<<128, 384, 0, stream>>>(gidec, dec_Whh, dec_bhh, sent, h2b);
    k_tl<<<1504, 256, 0, stream>>>(doc, h2b, fcWb, fc_b, tl);
    k_lse<<<376, 512, 0, stream>>>(h2b, fcWb, fc_b, parts);
    k_final<<<1, 1024, 0, stream>>>(parts, tl, out);
}